// Round 2
// baseline (57490.326 us; speedup 1.0000x reference)
//
#include <hip/hip_runtime.h>
#include <hip/hip_bf16.h>

#define S_LEN 16384
#define N_IN 23

// ---------------- dtype autodetect ----------------
// Reads the first `nsamp` 16-bit halfwords of `probe` (fc1_W). If the buffer
// is genuinely bf16, every sample is a weight with |w| < 0.5. If it is fp32,
// half the samples are fp32 mantissa low-halves -> random exponent fields ->
// with ~60 junk samples, some |v| > 1e4 (or NaN) almost surely.
__global__ void detect_kernel(const void* probe, int nsamp, int* flag)
{
    if (blockIdx.x == 0 && threadIdx.x == 0) {
        const unsigned short* p = (const unsigned short*)probe;
        int isbf16 = 1;
        for (int i = 0; i < nsamp; i++) {
            float v = __uint_as_float(((unsigned int)p[i]) << 16);
            if (!(fabsf(v) < 1e4f)) { isbf16 = 0; break; }
        }
        *flag = isbf16;
    }
}

// ---------------- ingest: convert all inputs to fp32 in ws ----------------
struct IngestArgs {
    const void* src[N_IN];
    float*      dst[N_IN];
    int         n[N_IN];
};

__global__ void ingest_kernel(IngestArgs args, const int* __restrict__ flag)
{
    const int isbf16 = *flag;
    const int tid    = blockIdx.x * blockDim.x + threadIdx.x;
    const int stride = gridDim.x * blockDim.x;
    for (int i = 0; i < N_IN; i++) {
        const int n = args.n[i];
        float* dst  = args.dst[i];
        if (isbf16) {
            const unsigned short* s = (const unsigned short*)args.src[i];
            for (int j = tid; j < n; j += stride)
                dst[j] = __uint_as_float(((unsigned int)s[j]) << 16);
        } else {
            const float* s = (const float*)args.src[i];
            for (int j = tid; j < n; j += stride)
                dst[j] = s[j];
        }
    }
}

// ---------------- fc1 + fc2 (parallel, thread per sequence position) ----------------
__global__ void fc12_kernel(const float* __restrict__ x,
                            const float* __restrict__ W1, const float* __restrict__ b1,
                            const float* __restrict__ W2, const float* __restrict__ b2,
                            float* __restrict__ h2out)
{
    int s = blockIdx.x * blockDim.x + threadIdx.x;
    if (s >= S_LEN) return;
    float xin[6];
#pragma unroll
    for (int k = 0; k < 6; k++) xin[k] = x[s * 6 + k];
    float h1[20];
#pragma unroll
    for (int j = 0; j < 20; j++) {
        float a = b1[j];
#pragma unroll
        for (int k = 0; k < 6; k++) a += W1[j * 6 + k] * xin[k];
        h1[j] = a > 0.f ? a : 0.f;
    }
#pragma unroll
    for (int j = 0; j < 20; j++) {
        float a = b2[j];
#pragma unroll
        for (int k = 0; k < 20; k++) a += W2[j * 20 + k] * h1[k];
        h2out[s * 20 + j] = a > 0.f ? a : 0.f;
    }
}

// -------- input-projection precompute: xw[s,g] = bih[g]+bhh[g] + Wih[g,:].in[s,:] -----
template <int DIN, int NG>
__global__ void xw_kernel(const float* __restrict__ in,
                          const float* __restrict__ Wih,
                          const float* __restrict__ bih,
                          const float* __restrict__ bhh,
                          float* __restrict__ xw)
{
    int s = blockIdx.x * blockDim.x + threadIdx.x;
    if (s >= S_LEN) return;
    float inv[DIN];
#pragma unroll
    for (int k = 0; k < DIN; k++) inv[k] = in[s * DIN + k];
    for (int g = 0; g < NG; g++) {
        float a = bih[g] + bhh[g];
#pragma unroll
        for (int k = 0; k < DIN; k++) a += Wih[g * DIN + k] * inv[k];
        xw[s * NG + g] = a;
    }
}

// ---------------- LSTM scan: single workgroup, 256 threads ----------------
// threads 0..191: gate rows (Whh row resident in VGPRs); threads 192..239: c/h update.
__global__ void __launch_bounds__(256, 1)
lstm_scan_kernel(const float* __restrict__ xw,   // [S, 192] precomputed input proj + biases
                 const float* __restrict__ Whh,  // [192, 48]
                 float* __restrict__ hseq)       // [S, 48] output
{
    const int t = threadIdx.x;
    __shared__ float h_sh[48];
    __shared__ float gates[192];

    float wrow[48];
    const bool active = (t < 192);
    if (active) {
#pragma unroll
        for (int k = 0; k < 48; k++) wrow[k] = Whh[t * 48 + k];
    }
    if (t < 48) h_sh[t] = 0.f;
    float c = 0.f;  // lives in threads 192..239 (j = t-192)
    const bool is_tanh_gate = (t >= 96 && t < 144);
    __syncthreads();

    float xwv = active ? xw[t] : 0.f;  // prefetch s=0

    for (int s = 0; s < S_LEN; s++) {
        float xwv_next = (active && (s + 1 < S_LEN)) ? xw[(s + 1) * 192 + t] : 0.f;
        if (active) {
            float a0 = 0.f, a1 = 0.f, a2 = 0.f, a3 = 0.f;
#pragma unroll
            for (int k = 0; k < 48; k += 4) {
                a0 += wrow[k + 0] * h_sh[k + 0];
                a1 += wrow[k + 1] * h_sh[k + 1];
                a2 += wrow[k + 2] * h_sh[k + 2];
                a3 += wrow[k + 3] * h_sh[k + 3];
            }
            float a = xwv + ((a0 + a1) + (a2 + a3));
            // i,f,o -> sigmoid ; g -> tanh via tanh(a)=2*sigmoid(2a)-1 (one exp)
            float xa = is_tanh_gate ? 2.f * a : a;
            float sv = 1.f / (1.f + expf(-xa));
            gates[t] = is_tanh_gate ? (2.f * sv - 1.f) : sv;
        }
        __syncthreads();
        if (t >= 192 && t < 240) {
            int j = t - 192;
            float iv = gates[j];
            float fv = gates[j + 48];
            float gv = gates[j + 96];
            float ov = gates[j + 144];
            c = fv * c + iv * gv;
            float h = ov * tanhf(c);
            h_sh[j] = h;
            hseq[s * 48 + j] = h;
        }
        __syncthreads();
        xwv = xwv_next;
    }
}

// ---------------- RNN scan: single workgroup, 1 wave ----------------
__global__ void __launch_bounds__(64, 1)
rnn_scan_kernel(const float* __restrict__ xw,   // [S, 24]
                const float* __restrict__ Whh,  // [24, 24]
                float* __restrict__ hseq)       // [S, 24]
{
    const int t = threadIdx.x;
    __shared__ float h_sh[24];
    float wrow[24];
    if (t < 24) {
#pragma unroll
        for (int k = 0; k < 24; k++) wrow[k] = Whh[t * 24 + k];
        h_sh[t] = 0.f;
    }
    __syncthreads();

    float xwv = (t < 24) ? xw[t] : 0.f;
    for (int s = 0; s < S_LEN; s++) {
        float xwv_next = (t < 24 && (s + 1 < S_LEN)) ? xw[(s + 1) * 24 + t] : 0.f;
        float h = 0.f;
        if (t < 24) {
            float a0 = 0.f, a1 = 0.f;
#pragma unroll
            for (int k = 0; k < 24; k += 2) {
                a0 += wrow[k + 0] * h_sh[k + 0];
                a1 += wrow[k + 1] * h_sh[k + 1];
            }
            h = tanhf(xwv + a0 + a1);
        }
        __syncthreads();  // all reads of h_sh done
        if (t < 24) {
            h_sh[t] = h;
            hseq[s * 24 + t] = h;
        }
        __syncthreads();
        xwv = xwv_next;
    }
}

// ---------------- epilogue: relu + fc4, bf16 or fp32 out per flag ----------------
__global__ void out_kernel(const float* __restrict__ hin,
                           const float* __restrict__ W,  // [2, 24]
                           const float* __restrict__ b,  // [2]
                           void* __restrict__ out,
                           const int* __restrict__ flag)
{
    int s = blockIdx.x * blockDim.x + threadIdx.x;
    if (s >= S_LEN) return;
    const int isbf16 = *flag;
    float h[24];
#pragma unroll
    for (int k = 0; k < 24; k++) {
        float v = hin[s * 24 + k];
        h[k] = v > 0.f ? v : 0.f;
    }
#pragma unroll
    for (int j = 0; j < 2; j++) {
        float a = b[j];
#pragma unroll
        for (int k = 0; k < 24; k++) a += W[j * 24 + k] * h[k];
        if (isbf16) ((__hip_bfloat16*)out)[s * 2 + j] = __float2bfloat16(a);
        else        ((float*)out)[s * 2 + j] = a;
    }
}

extern "C" void kernel_launch(void* const* d_in, const int* in_sizes, int n_in,
                              void* d_out, int out_size, void* d_ws, size_t ws_size,
                              hipStream_t stream)
{
    // ---- workspace layout (floats) ----
    float* ws = (float*)d_ws;
    int*  flag = (int*)d_ws;                 // [0] : dtype flag
    float* conv0 = ws + 16;                  // fp32 copies of all inputs

    // per-input fp32 copy pointers
    IngestArgs ia;
    float* conv[N_IN];
    {
        float* p = conv0;
        for (int i = 0; i < N_IN; i++) {
            conv[i] = p;
            ia.src[i] = d_in[i];
            ia.dst[i] = p;
            ia.n[i]   = in_sizes[i];
            p += in_sizes[i];
        }
        // pipeline buffers start after the conversion area
        // (total conv ~190,594 floats)
    }
    float* bufbase = conv0 + 200000;         // aligned-ish start for big buffers
    float* seqA = bufbase;                   // 16384*48 = 786432
    float* seqB = seqA + 786432;             // 786432
    float* xw   = seqB + 786432;             // 16384*192 = 3145728
    // overlays (lifetimes verified):
    float* h2   = seqB;                      // [S,20]  dead before seqB first written
    float* rnnA = seqB;                      // [S,24]  seqB dead after xw(lstm l=3)
    float* rnnB = seqA;                      // [S,24]  seqA dead after xw(rnn0)

    const float* x         = conv[0];
    const float* fc1_W     = conv[1];
    const float* fc1_b     = conv[2];
    const float* fc2_W     = conv[3];
    const float* fc2_b     = conv[4];
    const float* lstm0_Wih = conv[5];
    const float* lstm0_Whh = conv[6];
    const float* lstm0_bih = conv[7];
    const float* lstm0_bhh = conv[8];
    const float* lstmr_Wih = conv[9];
    const float* lstmr_Whh = conv[10];
    const float* lstmr_bih = conv[11];
    const float* lstmr_bhh = conv[12];
    const float* rnn0_Wih  = conv[13];
    const float* rnn0_Whh  = conv[14];
    const float* rnn0_bih  = conv[15];
    const float* rnn0_bhh  = conv[16];
    const float* rnn1_Wih  = conv[17];
    const float* rnn1_Whh  = conv[18];
    const float* rnn1_bih  = conv[19];
    const float* rnn1_bhh  = conv[20];
    const float* fc4_W     = conv[21];
    const float* fc4_b     = conv[22];

    const int TPB = 256;
    const int NB  = S_LEN / TPB;  // 64

    // dtype probe on fc1_W (in_sizes[1] halfwords are in-bounds for both dtypes)
    detect_kernel<<<1, 64, 0, stream>>>(d_in[1], in_sizes[1], flag);
    ingest_kernel<<<128, 256, 0, stream>>>(ia, flag);

    fc12_kernel<<<NB, TPB, 0, stream>>>(x, fc1_W, fc1_b, fc2_W, fc2_b, h2);

    // LSTM layer 0: 20 -> 48
    xw_kernel<20, 192><<<NB, TPB, 0, stream>>>(h2, lstm0_Wih, lstm0_bih, lstm0_bhh, xw);
    lstm_scan_kernel<<<1, 256, 0, stream>>>(xw, lstm0_Whh, seqA);

    // LSTM layers 1..4: 48 -> 48
    float* src = seqA;
    float* dst = seqB;
    for (int l = 0; l < 4; l++) {
        xw_kernel<48, 192><<<NB, TPB, 0, stream>>>(src,
                                                   lstmr_Wih + (size_t)l * 192 * 48,
                                                   lstmr_bih + (size_t)l * 192,
                                                   lstmr_bhh + (size_t)l * 192, xw);
        lstm_scan_kernel<<<1, 256, 0, stream>>>(xw, lstmr_Whh + (size_t)l * 192 * 48, dst);
        float* tmp = src; src = dst; dst = tmp;
    }
    // after loop, src == seqA holds the last LSTM output sequence

    // RNN layer 0: 48 -> 24
    xw_kernel<48, 24><<<NB, TPB, 0, stream>>>(src, rnn0_Wih, rnn0_bih, rnn0_bhh, xw);
    rnn_scan_kernel<<<1, 64, 0, stream>>>(xw, rnn0_Whh, rnnA);

    // RNN layer 1: 24 -> 24
    xw_kernel<24, 24><<<NB, TPB, 0, stream>>>(rnnA, rnn1_Wih, rnn1_bih, rnn1_bhh, xw);
    rnn_scan_kernel<<<1, 64, 0, stream>>>(xw, rnn1_Whh, rnnB);

    // epilogue
    out_kernel<<<NB, TPB, 0, stream>>>(rnnB, fc4_W, fc4_b, d_out, flag);
}

// Round 3
// 12659.750 us; speedup vs baseline: 4.5412x; 4.5412x over previous
//
#include <hip/hip_runtime.h>
#include <hip/hip_bf16.h>

#define S_LEN 16384
#define N_IN 23
#define CH 128
#define NCHUNK (S_LEN / CH)

// ---------------- fast activations (v_exp_f32 + v_rcp_f32) ----------------
__device__ __forceinline__ float fsig(float x) {
    return __builtin_amdgcn_rcpf(1.f + __expf(-x));   // safe: exp(+inf)->inf, rcp(inf)->0
}
__device__ __forceinline__ float ftanh_fast(float x) {
    float e = __expf(-2.f * fabsf(x));                // in (0,1]
    float r = (1.f - e) * __builtin_amdgcn_rcpf(1.f + e);
    return x >= 0.f ? r : -r;
}

// ---------------- dtype autodetect (bf16 vs fp32 input buffers) ----------------
__global__ void detect_kernel(const void* probe, int nsamp, int* flag)
{
    if (blockIdx.x == 0 && threadIdx.x == 0) {
        const unsigned short* p = (const unsigned short*)probe;
        int isbf16 = 1;
        for (int i = 0; i < nsamp; i++) {
            float v = __uint_as_float(((unsigned int)p[i]) << 16);
            if (!(fabsf(v) < 1e4f)) { isbf16 = 0; break; }
        }
        *flag = isbf16;
    }
}

// ---------------- ingest: convert all inputs to fp32 in ws ----------------
struct IngestArgs {
    const void* src[N_IN];
    float*      dst[N_IN];
    int         n[N_IN];
};

__global__ void ingest_kernel(IngestArgs args, const int* __restrict__ flag)
{
    const int isbf16 = *flag;
    const int tid    = blockIdx.x * blockDim.x + threadIdx.x;
    const int stride = gridDim.x * blockDim.x;
    for (int i = 0; i < N_IN; i++) {
        const int n = args.n[i];
        float* dst  = args.dst[i];
        if (isbf16) {
            const unsigned short* s = (const unsigned short*)args.src[i];
            for (int j = tid; j < n; j += stride)
                dst[j] = __uint_as_float(((unsigned int)s[j]) << 16);
        } else {
            const float* s = (const float*)args.src[i];
            for (int j = tid; j < n; j += stride)
                dst[j] = s[j];
        }
    }
}

// ---------------- zero the progress flags (ws is poisoned each launch) --------
__global__ void init_kernel(int* prog)
{
    int t = threadIdx.x;
    if (t < 7 * 64) prog[t] = 0;
}

// ---------------- fc1 + fc2 (parallel) ----------------
__global__ void fc12_kernel(const float* __restrict__ x,
                            const float* __restrict__ W1, const float* __restrict__ b1,
                            const float* __restrict__ W2, const float* __restrict__ b2,
                            float* __restrict__ h2out)
{
    int s = blockIdx.x * blockDim.x + threadIdx.x;
    if (s >= S_LEN) return;
    float xin[6];
#pragma unroll
    for (int k = 0; k < 6; k++) xin[k] = x[s * 6 + k];
    float h1[20];
#pragma unroll
    for (int j = 0; j < 20; j++) {
        float a = b1[j];
#pragma unroll
        for (int k = 0; k < 6; k++) a += W1[j * 6 + k] * xin[k];
        h1[j] = a > 0.f ? a : 0.f;
    }
#pragma unroll
    for (int j = 0; j < 20; j++) {
        float a = b2[j];
#pragma unroll
        for (int k = 0; k < 20; k++) a += W2[j * 20 + k] * h1[k];
        h2out[s * 20 + j] = a > 0.f ? a : 0.f;
    }
}

// ---------------- pipelined LSTM layer (one block) ----------------
// threads 0..191: gate g=t, holds Wih row [DIN] + Whh row [48] in VGPRs.
// threads 192..239: j=t-192, c/h update + x prefetch (2-step lead).
template <int DIN>
__device__ void lstm_block(const float* __restrict__ in,     // [S, DIN]
                           const float* __restrict__ Wih,    // [192, DIN]
                           const float* __restrict__ Whh,    // [192, 48]
                           const float* __restrict__ bih,
                           const float* __restrict__ bhh,
                           float* __restrict__ hseq,         // [S, 48]
                           int* my_prog, int* prev_prog)
{
    const int t = threadIdx.x;
    __shared__ __align__(16) float x_sh[48];
    __shared__ __align__(16) float h_sh[48];
    __shared__ float gates[192];

    float wih[DIN];
    float whh[48];
    float bsum = 0.f;
    const bool gate_t = (t < 192);
    if (gate_t) {
#pragma unroll
        for (int k = 0; k < DIN; k++) wih[k] = Wih[t * DIN + k];
#pragma unroll
        for (int k = 0; k < 48; k++) whh[k] = Whh[t * 48 + k];
        bsum = bih[t] + bhh[t];
    }
    if (t < 48) h_sh[t] = 0.f;
    const bool upd_t = (t >= 192 && t < 240);
    const int j = t - 192;
    const bool tanh_gate = (t >= 96 && t < 144);
    float ccell = 0.f;
    float xreg  = 0.f;

    const float4* x4 = (const float4*)x_sh;
    const float4* h4 = (const float4*)h_sh;

    for (int ch = 0; ch < NCHUNK; ch++) {
        if (prev_prog) {
            if (t == 0) {
                int need = ch + 2; if (need > NCHUNK) need = NCHUNK;
                while (__hip_atomic_load(prev_prog, __ATOMIC_ACQUIRE, __HIP_MEMORY_SCOPE_AGENT) < need)
                    __builtin_amdgcn_s_sleep(2);
            }
            __syncthreads();
        }
        if (ch == 0) {
            if (t < DIN) x_sh[t] = in[t];
            if (upd_t && j < DIN) xreg = in[DIN + j];
            __syncthreads();
        }
        const int s_end = ch * CH + CH;
        for (int s = ch * CH; s < s_end; s++) {
            if (gate_t) {
                float a0 = 0.f, a1 = 0.f, a2 = 0.f, a3 = 0.f;
#pragma unroll
                for (int k = 0; k < 12; k++) {
                    float4 hv = h4[k];
                    a0 += whh[4 * k + 0] * hv.x;
                    a1 += whh[4 * k + 1] * hv.y;
                    a2 += whh[4 * k + 2] * hv.z;
                    a3 += whh[4 * k + 3] * hv.w;
                }
#pragma unroll
                for (int k = 0; k < DIN / 4; k++) {
                    float4 xv = x4[k];
                    a0 += wih[4 * k + 0] * xv.x;
                    a1 += wih[4 * k + 1] * xv.y;
                    a2 += wih[4 * k + 2] * xv.z;
                    a3 += wih[4 * k + 3] * xv.w;
                }
                float a = bsum + ((a0 + a1) + (a2 + a3));
                // i,f,o: sigmoid; g: tanh(a) = 2*sigmoid(2a)-1 (NaN-safe)
                gates[t] = tanh_gate ? (2.f * fsig(2.f * a) - 1.f) : fsig(a);
            }
            __syncthreads();
            if (upd_t) {
                float iv = gates[j], fv = gates[j + 48], gv = gates[j + 96], ov = gates[j + 144];
                ccell = fv * ccell + iv * gv;
                float h = ov * ftanh_fast(ccell);
                h_sh[j] = h;
                hseq[s * 48 + j] = h;
                if (j < DIN) {
                    x_sh[j] = xreg;                    // x for step s+1
                    int nx = s + 2; if (nx > S_LEN - 1) nx = S_LEN - 1;
                    xreg = in[nx * DIN + j];           // x for step s+2
                }
            }
            __syncthreads();
        }
        if (t == 0)
            __hip_atomic_store(my_prog, ch + 1, __ATOMIC_RELEASE, __HIP_MEMORY_SCOPE_AGENT);
    }
}

// ---------------- pipelined tanh-RNN layer (one block, H=24) ----------------
template <int DIN>
__device__ void rnn_block(const float* __restrict__ in,     // [S, DIN]
                          const float* __restrict__ Wih,    // [24, DIN]
                          const float* __restrict__ Whh,    // [24, 24]
                          const float* __restrict__ bih,
                          const float* __restrict__ bhh,
                          float* __restrict__ hseq,         // [S, 24]
                          int* my_prog, int* prev_prog)
{
    const int t = threadIdx.x;
    __shared__ __align__(16) float x_sh[48];
    __shared__ __align__(16) float h_sh[24];

    float wih[DIN];
    float whh[24];
    float bsum = 0.f;
    const bool gate_t = (t < 24);
    if (gate_t) {
#pragma unroll
        for (int k = 0; k < DIN; k++) wih[k] = Wih[t * DIN + k];
#pragma unroll
        for (int k = 0; k < 24; k++) whh[k] = Whh[t * 24 + k];
        bsum = bih[t] + bhh[t];
        h_sh[t] = 0.f;
    }
    const bool pf_t = (t >= 64 && t < 64 + DIN);
    const int j = t - 64;
    float xreg = 0.f;

    const float4* x4 = (const float4*)x_sh;
    const float4* h4 = (const float4*)h_sh;

    for (int ch = 0; ch < NCHUNK; ch++) {
        if (prev_prog) {
            if (t == 0) {
                int need = ch + 2; if (need > NCHUNK) need = NCHUNK;
                while (__hip_atomic_load(prev_prog, __ATOMIC_ACQUIRE, __HIP_MEMORY_SCOPE_AGENT) < need)
                    __builtin_amdgcn_s_sleep(2);
            }
            __syncthreads();
        }
        if (ch == 0) {
            if (t < DIN) x_sh[t] = in[t];
            if (pf_t) xreg = in[DIN + j];
            __syncthreads();
        }
        const int s_end = ch * CH + CH;
        for (int s = ch * CH; s < s_end; s++) {
            float hnew = 0.f;
            if (gate_t) {
                float a0 = 0.f, a1 = 0.f, a2 = 0.f, a3 = 0.f;
#pragma unroll
                for (int k = 0; k < 6; k++) {
                    float4 hv = h4[k];
                    a0 += whh[4 * k + 0] * hv.x;
                    a1 += whh[4 * k + 1] * hv.y;
                    a2 += whh[4 * k + 2] * hv.z;
                    a3 += whh[4 * k + 3] * hv.w;
                }
#pragma unroll
                for (int k = 0; k < DIN / 4; k++) {
                    float4 xv = x4[k];
                    a0 += wih[4 * k + 0] * xv.x;
                    a1 += wih[4 * k + 1] * xv.y;
                    a2 += wih[4 * k + 2] * xv.z;
                    a3 += wih[4 * k + 3] * xv.w;
                }
                hnew = ftanh_fast(bsum + ((a0 + a1) + (a2 + a3)));
            }
            __syncthreads();
            if (gate_t) {
                h_sh[t] = hnew;
                hseq[s * 24 + t] = hnew;
            }
            if (pf_t) {
                x_sh[j] = xreg;
                int nx = s + 2; if (nx > S_LEN - 1) nx = S_LEN - 1;
                xreg = in[nx * DIN + j];
            }
            __syncthreads();
        }
        if (t == 0)
            __hip_atomic_store(my_prog, ch + 1, __ATOMIC_RELEASE, __HIP_MEMORY_SCOPE_AGENT);
    }
}

// ---------------- the 7-layer pipeline megakernel ----------------
struct PipeArgs {
    const float* h2;
    const float* l0_Wih; const float* l0_Whh; const float* l0_bih; const float* l0_bhh;
    const float* lr_Wih; const float* lr_Whh; const float* lr_bih; const float* lr_bhh;
    const float* r0_Wih; const float* r0_Whh; const float* r0_bih; const float* r0_bhh;
    const float* r1_Wih; const float* r1_Whh; const float* r1_bih; const float* r1_bhh;
    float* seq0; float* seq1; float* seq2; float* seq3; float* seq4;
    float* rnnA; float* rnnB;
    int* prog;   // progress[l] at prog[l*64]
};

__global__ void __launch_bounds__(256, 1) pipeline_kernel(PipeArgs a)
{
    const int b = blockIdx.x;
    float* seqs[5] = {a.seq0, a.seq1, a.seq2, a.seq3, a.seq4};
    if (b == 0) {
        lstm_block<20>(a.h2, a.l0_Wih, a.l0_Whh, a.l0_bih, a.l0_bhh,
                       a.seq0, a.prog + 0, nullptr);
    } else if (b <= 4) {
        const int l = b - 1;
        lstm_block<48>(seqs[l],
                       a.lr_Wih + (size_t)l * 192 * 48,
                       a.lr_Whh + (size_t)l * 192 * 48,
                       a.lr_bih + (size_t)l * 192,
                       a.lr_bhh + (size_t)l * 192,
                       seqs[l + 1], a.prog + b * 64, a.prog + (b - 1) * 64);
    } else if (b == 5) {
        rnn_block<48>(a.seq4, a.r0_Wih, a.r0_Whh, a.r0_bih, a.r0_bhh,
                      a.rnnA, a.prog + 5 * 64, a.prog + 4 * 64);
    } else {
        rnn_block<24>(a.rnnA, a.r1_Wih, a.r1_Whh, a.r1_bih, a.r1_bhh,
                      a.rnnB, a.prog + 6 * 64, a.prog + 5 * 64);
    }
}

// ---------------- epilogue: relu + fc4, bf16 or fp32 out per flag ----------------
__global__ void out_kernel(const float* __restrict__ hin,
                           const float* __restrict__ W,  // [2, 24]
                           const float* __restrict__ b,  // [2]
                           void* __restrict__ out,
                           const int* __restrict__ flag)
{
    int s = blockIdx.x * blockDim.x + threadIdx.x;
    if (s >= S_LEN) return;
    const int isbf16 = *flag;
    float h[24];
#pragma unroll
    for (int k = 0; k < 24; k++) {
        float v = hin[s * 24 + k];
        h[k] = v > 0.f ? v : 0.f;
    }
#pragma unroll
    for (int j = 0; j < 2; j++) {
        float a = b[j];
#pragma unroll
        for (int k = 0; k < 24; k++) a += W[j * 24 + k] * h[k];
        if (isbf16) ((__hip_bfloat16*)out)[s * 2 + j] = __float2bfloat16(a);
        else        ((float*)out)[s * 2 + j] = a;
    }
}

extern "C" void kernel_launch(void* const* d_in, const int* in_sizes, int n_in,
                              void* d_out, int out_size, void* d_ws, size_t ws_size,
                              hipStream_t stream)
{
    // ---- workspace layout ----
    int*   ip    = (int*)d_ws;        // ip[0]: dtype flag; ip[256 + l*64]: progress[l]
    int*   flag  = ip;
    int*   prog  = ip + 256;
    float* ws    = (float*)d_ws;
    float* conv0 = ws + 1024;

    IngestArgs ia;
    float* conv[N_IN];
    {
        float* p = conv0;
        for (int i = 0; i < N_IN; i++) {
            conv[i] = p;
            ia.src[i] = d_in[i];
            ia.dst[i] = p;
            ia.n[i]   = in_sizes[i];
            p += in_sizes[i];
        }
    }
    float* h2   = conv0 + 191000;       // [S,20]  327,680
    float* seq0 = h2 + 327680;          // 5 x [S,48] = 5 x 786,432
    float* seq1 = seq0 + 786432;
    float* seq2 = seq1 + 786432;
    float* seq3 = seq2 + 786432;
    float* seq4 = seq3 + 786432;
    float* rnnA = seq4 + 786432;        // [S,24] 393,216
    float* rnnB = rnnA + 393216;        // [S,24] 393,216

    const int TPB = 256;
    const int NB  = S_LEN / TPB;  // 64

    detect_kernel<<<1, 64, 0, stream>>>(d_in[1], in_sizes[1], flag);
    ingest_kernel<<<128, 256, 0, stream>>>(ia, flag);
    init_kernel<<<1, 512, 0, stream>>>(prog);

    fc12_kernel<<<NB, TPB, 0, stream>>>(conv[0], conv[1], conv[2], conv[3], conv[4], h2);

    PipeArgs pa;
    pa.h2 = h2;
    pa.l0_Wih = conv[5];  pa.l0_Whh = conv[6];  pa.l0_bih = conv[7];  pa.l0_bhh = conv[8];
    pa.lr_Wih = conv[9];  pa.lr_Whh = conv[10]; pa.lr_bih = conv[11]; pa.lr_bhh = conv[12];
    pa.r0_Wih = conv[13]; pa.r0_Whh = conv[14]; pa.r0_bih = conv[15]; pa.r0_bhh = conv[16];
    pa.r1_Wih = conv[17]; pa.r1_Whh = conv[18]; pa.r1_bih = conv[19]; pa.r1_bhh = conv[20];
    pa.seq0 = seq0; pa.seq1 = seq1; pa.seq2 = seq2; pa.seq3 = seq3; pa.seq4 = seq4;
    pa.rnnA = rnnA; pa.rnnB = rnnB;
    pa.prog = prog;

    pipeline_kernel<<<7, 256, 0, stream>>>(pa);

    out_kernel<<<NB, TPB, 0, stream>>>(rnnB, conv[21], conv[22], d_out, flag);
}

// Round 4
// 10391.670 us; speedup vs baseline: 5.5323x; 1.2183x over previous
//
#include <hip/hip_runtime.h>
#include <hip/hip_bf16.h>

#define S_LEN 16384
#define N_IN 23
#define CH 128
#define NCHUNK (S_LEN / CH)

// ---------------- fast activations (v_exp_f32 + v_rcp_f32) ----------------
__device__ __forceinline__ float fsig(float x) {
    return __builtin_amdgcn_rcpf(1.f + __expf(-x));   // exp(+inf)->inf, rcp(inf)->0: safe
}
__device__ __forceinline__ float ftanh_fast(float x) {
    float e = __expf(-2.f * fabsf(x));                // in (0,1]
    float r = (1.f - e) * __builtin_amdgcn_rcpf(1.f + e);
    return x >= 0.f ? r : -r;
}

// ---------------- dtype autodetect (bf16 vs fp32 input buffers) ----------------
__global__ void detect_kernel(const void* probe, int nsamp, int* flag)
{
    if (blockIdx.x == 0 && threadIdx.x == 0) {
        const unsigned short* p = (const unsigned short*)probe;
        int isbf16 = 1;
        for (int i = 0; i < nsamp; i++) {
            float v = __uint_as_float(((unsigned int)p[i]) << 16);
            if (!(fabsf(v) < 1e4f)) { isbf16 = 0; break; }
        }
        *flag = isbf16;
    }
}

// ---------------- ingest: convert all inputs to fp32 in ws ----------------
struct IngestArgs {
    const void* src[N_IN];
    float*      dst[N_IN];
    int         n[N_IN];
};

__global__ void ingest_kernel(IngestArgs args, const int* __restrict__ flag)
{
    const int isbf16 = *flag;
    const int tid    = blockIdx.x * blockDim.x + threadIdx.x;
    const int stride = gridDim.x * blockDim.x;
    for (int i = 0; i < N_IN; i++) {
        const int n = args.n[i];
        float* dst  = args.dst[i];
        if (isbf16) {
            const unsigned short* s = (const unsigned short*)args.src[i];
            for (int j = tid; j < n; j += stride)
                dst[j] = __uint_as_float(((unsigned int)s[j]) << 16);
        } else {
            const float* s = (const float*)args.src[i];
            for (int j = tid; j < n; j += stride)
                dst[j] = s[j];
        }
    }
}

// ---------------- zero the progress flags (ws is poisoned each launch) --------
__global__ void init_kernel(int* prog)
{
    int t = threadIdx.x;
    if (t < 7 * 64) prog[t] = 0;
}

// ---------------- fc1 + fc2 (parallel) ----------------
__global__ void fc12_kernel(const float* __restrict__ x,
                            const float* __restrict__ W1, const float* __restrict__ b1,
                            const float* __restrict__ W2, const float* __restrict__ b2,
                            float* __restrict__ h2out)
{
    int s = blockIdx.x * blockDim.x + threadIdx.x;
    if (s >= S_LEN) return;
    float xin[6];
#pragma unroll
    for (int k = 0; k < 6; k++) xin[k] = x[s * 6 + k];
    float h1[20];
#pragma unroll
    for (int j = 0; j < 20; j++) {
        float a = b1[j];
#pragma unroll
        for (int k = 0; k < 6; k++) a += W1[j * 6 + k] * xin[k];
        h1[j] = a > 0.f ? a : 0.f;
    }
#pragma unroll
    for (int j = 0; j < 20; j++) {
        float a = b2[j];
#pragma unroll
        for (int k = 0; k < 20; k++) a += W2[j * 20 + k] * h1[k];
        h2out[s * 20 + j] = a > 0.f ? a : 0.f;
    }
}

// ---------------- pipelined LSTM layer (one block), chunked LDS staging -------
// smem partition: x_chunk[CH*DIN] | h_hist[CH*48] | h_sh[48] | gates[192]
// threads 0..191: gate g=t (Wih row + Whh row in VGPRs); 192..239: c/h update.
// NO global memory ops inside the per-step loop.
template <int DIN>
__device__ void lstm_block(const float* __restrict__ in,     // [S, DIN]
                           const float* __restrict__ Wih,    // [192, DIN]
                           const float* __restrict__ Whh,    // [192, 48]
                           const float* __restrict__ bih,
                           const float* __restrict__ bhh,
                           float* __restrict__ hseq,         // [S, 48]
                           int* my_prog, int* prev_prog, float* smem)
{
    const int t = threadIdx.x;
    float* x_chunk = smem;                        // CH*DIN
    float* h_hist  = smem + CH * DIN;             // CH*48
    float* h_sh    = h_hist + CH * 48;            // 48
    float* gates   = h_sh + 48;                   // 192

    float wih[DIN];
    float whh[48];
    float bsum = 0.f;
    const bool gate_t = (t < 192);
    if (gate_t) {
#pragma unroll
        for (int k = 0; k < DIN; k++) wih[k] = Wih[t * DIN + k];
#pragma unroll
        for (int k = 0; k < 48; k++) whh[k] = Whh[t * 48 + k];
        bsum = bih[t] + bhh[t];
    }
    if (t < 48) h_sh[t] = 0.f;
    const bool upd_t = (t >= 192 && t < 240);
    const int j = t - 192;
    const bool tanh_gate = (t >= 96 && t < 144);
    float ccell = 0.f;

    const float4* h4 = (const float4*)h_sh;
    __syncthreads();

    for (int ch = 0; ch < NCHUNK; ch++) {
        if (prev_prog && t == 0) {
            while (__hip_atomic_load(prev_prog, __ATOMIC_ACQUIRE, __HIP_MEMORY_SCOPE_AGENT) < ch + 1)
                __builtin_amdgcn_s_sleep(2);
        }
        __syncthreads();
        // cooperative input-chunk load (global -> LDS), float4-coalesced
        {
            const float4* gsrc = (const float4*)(in + (size_t)ch * CH * DIN);
            float4* ldst = (float4*)x_chunk;
            for (int i = t; i < CH * DIN / 4; i += 256) ldst[i] = gsrc[i];
        }
        __syncthreads();

        for (int sl = 0; sl < CH; sl++) {
            if (gate_t) {
                const float4* x4 = (const float4*)(x_chunk + sl * DIN);
                float a0 = 0.f, a1 = 0.f, a2 = 0.f, a3 = 0.f;
#pragma unroll
                for (int k = 0; k < 12; k++) {
                    float4 hv = h4[k];
                    a0 += whh[4 * k + 0] * hv.x;
                    a1 += whh[4 * k + 1] * hv.y;
                    a2 += whh[4 * k + 2] * hv.z;
                    a3 += whh[4 * k + 3] * hv.w;
                }
#pragma unroll
                for (int k = 0; k < DIN / 4; k++) {
                    float4 xv = x4[k];
                    a0 += wih[4 * k + 0] * xv.x;
                    a1 += wih[4 * k + 1] * xv.y;
                    a2 += wih[4 * k + 2] * xv.z;
                    a3 += wih[4 * k + 3] * xv.w;
                }
                float a = bsum + ((a0 + a1) + (a2 + a3));
                // i,f,o: sigmoid; g: tanh(a)=2*sigmoid(2a)-1 (NaN-safe)
                gates[t] = tanh_gate ? (2.f * fsig(2.f * a) - 1.f) : fsig(a);
            }
            __syncthreads();
            if (upd_t) {
                float iv = gates[j], fv = gates[j + 48], gv = gates[j + 96], ov = gates[j + 144];
                ccell = fv * ccell + iv * gv;
                float h = ov * ftanh_fast(ccell);
                h_sh[j] = h;
                h_hist[sl * 48 + j] = h;
            }
            __syncthreads();
        }

        // cooperative output-chunk store (LDS -> global)
        {
            const float4* lsrc = (const float4*)h_hist;
            float4* gdst = (float4*)(hseq + (size_t)ch * CH * 48);
            for (int i = t; i < CH * 12; i += 256) gdst[i] = lsrc[i];
        }
        __syncthreads();   // drains each wave's vmcnt before progress is posted
        if (t == 0)
            __hip_atomic_store(my_prog, ch + 1, __ATOMIC_RELEASE, __HIP_MEMORY_SCOPE_AGENT);
    }
}

// ---------------- pipelined tanh-RNN layer (one block, H=24) ------------------
// Step loop runs on wave 0 only (lanes 0..23), barrier-free (wave lockstep).
template <int DIN>
__device__ void rnn_block(const float* __restrict__ in,     // [S, DIN]
                          const float* __restrict__ Wih,    // [24, DIN]
                          const float* __restrict__ Whh,    // [24, 24]
                          const float* __restrict__ bih,
                          const float* __restrict__ bhh,
                          float* __restrict__ hseq,         // [S, 24]
                          int* my_prog, int* prev_prog, float* smem)
{
    const int t = threadIdx.x;
    float* x_chunk = smem;                        // CH*DIN
    float* h_hist  = smem + CH * DIN;             // CH*24
    float* h_sh    = h_hist + CH * 24;            // 24

    float wih[DIN];
    float whh[24];
    float bsum = 0.f;
    const bool gate_t = (t < 24);
    if (gate_t) {
#pragma unroll
        for (int k = 0; k < DIN; k++) wih[k] = Wih[t * DIN + k];
#pragma unroll
        for (int k = 0; k < 24; k++) whh[k] = Whh[t * 24 + k];
        bsum = bih[t] + bhh[t];
        h_sh[t] = 0.f;
    }
    const float4* h4 = (const float4*)h_sh;
    __syncthreads();

    for (int ch = 0; ch < NCHUNK; ch++) {
        if (prev_prog && t == 0) {
            while (__hip_atomic_load(prev_prog, __ATOMIC_ACQUIRE, __HIP_MEMORY_SCOPE_AGENT) < ch + 1)
                __builtin_amdgcn_s_sleep(2);
        }
        __syncthreads();
        {
            const float4* gsrc = (const float4*)(in + (size_t)ch * CH * DIN);
            float4* ldst = (float4*)x_chunk;
            for (int i = t; i < CH * DIN / 4; i += 256) ldst[i] = gsrc[i];
        }
        __syncthreads();

        if (t < 64) {
            for (int sl = 0; sl < CH; sl++) {
                if (gate_t) {
                    const float4* x4 = (const float4*)(x_chunk + sl * DIN);
                    float a0 = 0.f, a1 = 0.f, a2 = 0.f, a3 = 0.f;
#pragma unroll
                    for (int k = 0; k < 6; k++) {
                        float4 hv = h4[k];
                        a0 += whh[4 * k + 0] * hv.x;
                        a1 += whh[4 * k + 1] * hv.y;
                        a2 += whh[4 * k + 2] * hv.z;
                        a3 += whh[4 * k + 3] * hv.w;
                    }
#pragma unroll
                    for (int k = 0; k < DIN / 4; k++) {
                        float4 xv = x4[k];
                        a0 += wih[4 * k + 0] * xv.x;
                        a1 += wih[4 * k + 1] * xv.y;
                        a2 += wih[4 * k + 2] * xv.z;
                        a3 += wih[4 * k + 3] * xv.w;
                    }
                    float hnew = ftanh_fast(bsum + ((a0 + a1) + (a2 + a3)));
                    // all lanes' ds_reads of h_sh precede this write in the wave's
                    // instruction stream -> no intra-wave race, no barrier needed
                    h_sh[t] = hnew;
                    h_hist[sl * 24 + t] = hnew;
                }
            }
        }
        __syncthreads();

        {
            const float4* lsrc = (const float4*)h_hist;
            float4* gdst = (float4*)(hseq + (size_t)ch * CH * 24);
            for (int i = t; i < CH * 6; i += 256) gdst[i] = lsrc[i];
        }
        __syncthreads();
        if (t == 0)
            __hip_atomic_store(my_prog, ch + 1, __ATOMIC_RELEASE, __HIP_MEMORY_SCOPE_AGENT);
    }
}

// ---------------- the 7-layer pipeline megakernel ----------------
struct PipeArgs {
    const float* h2;
    const float* l0_Wih; const float* l0_Whh; const float* l0_bih; const float* l0_bhh;
    const float* lr_Wih; const float* lr_Whh; const float* lr_bih; const float* lr_bhh;
    const float* r0_Wih; const float* r0_Whh; const float* r0_bih; const float* r0_bhh;
    const float* r1_Wih; const float* r1_Whh; const float* r1_bih; const float* r1_bhh;
    float* seq0; float* seq1; float* seq2; float* seq3; float* seq4;
    float* rnnA; float* rnnB;
    int* prog;   // progress[l] at prog[l*64]
};

__global__ void __launch_bounds__(256, 1) pipeline_kernel(PipeArgs a)
{
    // one shared arena, partitioned per stage (worst case lstm<48>: 12528 floats)
    __shared__ float smem[12544];
    const int b = blockIdx.x;
    float* seqs[5] = {a.seq0, a.seq1, a.seq2, a.seq3, a.seq4};
    if (b == 0) {
        lstm_block<20>(a.h2, a.l0_Wih, a.l0_Whh, a.l0_bih, a.l0_bhh,
                       a.seq0, a.prog + 0, nullptr, smem);
    } else if (b <= 4) {
        const int l = b - 1;
        lstm_block<48>(seqs[l],
                       a.lr_Wih + (size_t)l * 192 * 48,
                       a.lr_Whh + (size_t)l * 192 * 48,
                       a.lr_bih + (size_t)l * 192,
                       a.lr_bhh + (size_t)l * 192,
                       seqs[l + 1], a.prog + b * 64, a.prog + (b - 1) * 64, smem);
    } else if (b == 5) {
        rnn_block<48>(a.seq4, a.r0_Wih, a.r0_Whh, a.r0_bih, a.r0_bhh,
                      a.rnnA, a.prog + 5 * 64, a.prog + 4 * 64, smem);
    } else {
        rnn_block<24>(a.rnnA, a.r1_Wih, a.r1_Whh, a.r1_bih, a.r1_bhh,
                      a.rnnB, a.prog + 6 * 64, a.prog + 5 * 64, smem);
    }
}

// ---------------- epilogue: relu + fc4, bf16 or fp32 out per flag ----------------
__global__ void out_kernel(const float* __restrict__ hin,
                           const float* __restrict__ W,  // [2, 24]
                           const float* __restrict__ b,  // [2]
                           void* __restrict__ out,
                           const int* __restrict__ flag)
{
    int s = blockIdx.x * blockDim.x + threadIdx.x;
    if (s >= S_LEN) return;
    const int isbf16 = *flag;
    float h[24];
#pragma unroll
    for (int k = 0; k < 24; k++) {
        float v = hin[s * 24 + k];
        h[k] = v > 0.f ? v : 0.f;
    }
#pragma unroll
    for (int j = 0; j < 2; j++) {
        float a = b[j];
#pragma unroll
        for (int k = 0; k < 24; k++) a += W[j * 24 + k] * h[k];
        if (isbf16) ((__hip_bfloat16*)out)[s * 2 + j] = __float2bfloat16(a);
        else        ((float*)out)[s * 2 + j] = a;
    }
}

extern "C" void kernel_launch(void* const* d_in, const int* in_sizes, int n_in,
                              void* d_out, int out_size, void* d_ws, size_t ws_size,
                              hipStream_t stream)
{
    // ---- workspace layout ----
    int*   ip    = (int*)d_ws;        // ip[0]: dtype flag; ip[256 + l*64]: progress[l]
    int*   flag  = ip;
    int*   prog  = ip + 256;
    float* ws    = (float*)d_ws;
    float* conv0 = ws + 1024;

    IngestArgs ia;
    float* conv[N_IN];
    {
        float* p = conv0;
        for (int i = 0; i < N_IN; i++) {
            conv[i] = p;
            ia.src[i] = d_in[i];
            ia.dst[i] = p;
            ia.n[i]   = in_sizes[i];
            p += in_sizes[i];
        }
    }
    float* h2   = conv0 + 191000;       // [S,20]  327,680
    float* seq0 = h2 + 327680;          // 5 x [S,48]
    float* seq1 = seq0 + 786432;
    float* seq2 = seq1 + 786432;
    float* seq3 = seq2 + 786432;
    float* seq4 = seq3 + 786432;
    float* rnnA = seq4 + 786432;        // [S,24]
    float* rnnB = rnnA + 393216;        // [S,24]

    const int TPB = 256;
    const int NB  = S_LEN / TPB;  // 64

    detect_kernel<<<1, 64, 0, stream>>>(d_in[1], in_sizes[1], flag);
    ingest_kernel<<<128, 256, 0, stream>>>(ia, flag);
    init_kernel<<<1, 512, 0, stream>>>(prog);

    fc12_kernel<<<NB, TPB, 0, stream>>>(conv[0], conv[1], conv[2], conv[3], conv[4], h2);

    PipeArgs pa;
    pa.h2 = h2;
    pa.l0_Wih = conv[5];  pa.l0_Whh = conv[6];  pa.l0_bih = conv[7];  pa.l0_bhh = conv[8];
    pa.lr_Wih = conv[9];  pa.lr_Whh = conv[10]; pa.lr_bih = conv[11]; pa.lr_bhh = conv[12];
    pa.r0_Wih = conv[13]; pa.r0_Whh = conv[14]; pa.r0_bih = conv[15]; pa.r0_bhh = conv[16];
    pa.r1_Wih = conv[17]; pa.r1_Whh = conv[18]; pa.r1_bih = conv[19]; pa.r1_bhh = conv[20];
    pa.seq0 = seq0; pa.seq1 = seq1; pa.seq2 = seq2; pa.seq3 = seq3; pa.seq4 = seq4;
    pa.rnnA = rnnA; pa.rnnB = rnnB;
    pa.prog = prog;

    pipeline_kernel<<<7, 256, 0, stream>>>(pa);

    out_kernel<<<NB, TPB, 0, stream>>>(rnnB, conv[21], conv[22], d_out, flag);
}